// Round 6
// baseline (396.727 us; speedup 1.0000x reference)
//
#include <hip/hip_runtime.h>
#include <hip/hip_bf16.h>

typedef __hip_bfloat16 bf16;
typedef __bf16 bf16x8 __attribute__((ext_vector_type(8)));
typedef float  f32x4  __attribute__((ext_vector_type(4)));
typedef unsigned short u16x8 __attribute__((ext_vector_type(8)));

#define C_IN  512
#define N_SP  1024
#define BATCH 32

// Mixed-dtype accessors: f32 flag selects fp32 or bf16 view of the SAME buffer.
__device__ __forceinline__ float ldmix(const void* p, size_t i, int f32) {
    return f32 ? ((const float*)p)[i] : __bfloat162float(((const bf16*)p)[i]);
}
__device__ __forceinline__ void stmix(void* p, size_t i, float v, int f32) {
    if (f32) ((float*)p)[i] = v;
    else     ((bf16*)p)[i] = __float2bfloat16(v);
}
__device__ __forceinline__ unsigned short bfbits(float f) {
    bf16 t = __float2bfloat16(f);
    return *reinterpret_cast<unsigned short*>(&t);
}
__device__ __forceinline__ float bf2f(unsigned short h) {
    union { unsigned u; float f; } c; c.u = ((unsigned)h) << 16; return c.f;
}
// 8 consecutive elements of W starting at element index `base` (base % 8 == 0).
__device__ __forceinline__ void ldvec8(const void* W, size_t base, int f32, float v[8]) {
    if (f32) {
        const float4* p = reinterpret_cast<const float4*>((const float*)W + base);
        float4 a = p[0], b = p[1];
        v[0] = a.x; v[1] = a.y; v[2] = a.z; v[3] = a.w;
        v[4] = b.x; v[5] = b.y; v[6] = b.z; v[7] = b.w;
    } else {
        u16x8 h = *reinterpret_cast<const u16x8*>((const bf16*)W + base);
#pragma unroll
        for (int j = 0; j < 8; ++j) v[j] = bf2f(h[j]);
    }
}

// ---------------------------------------------------------------------------
// Async global->LDS staging (gfx950). LDS dest = wave-uniform base + lane*16
// (linear). Swizzled LDS layout achieved by pre-swizzling the per-lane GLOBAL
// source; the ds_read applies the same XOR (both-sides-or-neither, rule #21).
// ---------------------------------------------------------------------------
__device__ __forceinline__ void gload_lds16(const bf16* g, void* l) {
    __builtin_amdgcn_global_load_lds(
        (__attribute__((address_space(1))) void*)(g),
        (__attribute__((address_space(3))) void*)(l),
        16, 0, 0);
}

// --- BK=32 staging (64-row tile), used by k_qkv_qk (R4-verified) -----------
// Swizzle: 16B chunk s of row r stored at chunk s ^ ((r>>1)&3) (4 chunks/row).
#define STAGE64(LDS, GROW, GPITCH, K0) do {                                    \
    int _c = (wave << 6) + lane; int _r = _c >> 2;                             \
    int _s = (_c & 3) ^ ((_r >> 1) & 3);                                       \
    gload_lds16((GROW) + (size_t)_r * (GPITCH) + (K0) + _s * 8,                \
                (char*)(LDS) + (wave << 10));                                  \
} while (0)

__device__ __forceinline__ bf16x8 swz_frag(const void* tile, int row, int quad) {
    return *(const bf16x8*)((const char*)tile + (row << 6) +
                            ((quad ^ ((row >> 1) & 3)) << 4));
}

// --- 4-phase counted schedule for 256-sq GEMMs -----------------------------
// LDS = 4 slots x 32 KB. Slot (t&1)*2 + kh holds K-half kh of K-tile t:
//   A[256 rows][32 cols] @ +0, B[256][32] @ +16384. Rows are 64 B = 4 chunks;
//   swizzle: phys chunk = logical ^ ((row>>1)&3)  (2-way, conflict-free).
// Staging one slot = 4 gload_lds per wave (2 A + 2 B).
#define STGUNIT(SLOT, AROW, APITCH, BROW, BPITCH, KOFF) do {                   \
    char* _ub = lds + (size_t)(SLOT) * 32768;                                  \
    _Pragma("unroll")                                                          \
    for (int _i = 0; _i < 2; ++_i) {                                           \
        int _c = ((wave * 2 + _i) << 6) + lane;                                \
        int _r = _c >> 2; int _s = (_c & 3) ^ ((_r >> 1) & 3);                 \
        gload_lds16((AROW) + (size_t)_r * (APITCH) + (KOFF) + _s * 8,          \
                    _ub + ((wave * 2 + _i) << 10));                            \
    }                                                                          \
    _Pragma("unroll")                                                          \
    for (int _i = 0; _i < 2; ++_i) {                                           \
        int _c = ((wave * 2 + _i) << 6) + lane;                                \
        int _r = _c >> 2; int _s = (_c & 3) ^ ((_r >> 1) & 3);                 \
        gload_lds16((BROW) + (size_t)_r * (BPITCH) + (KOFF) + _s * 8,          \
                    _ub + 16384 + ((wave * 2 + _i) << 10));                    \
    }                                                                          \
} while (0)

__device__ __forceinline__ bf16x8 frag32(const char* part, int row, int quad) {
    return *(const bf16x8*)(part + (row << 6) +
                            ((quad ^ ((row >> 1) & 3)) << 4));
}

// Counted wait: allow the newest N VMEM ops to stay in flight (oldest-first
// vmcnt retirement guarantees everything older has landed), then barrier.
#define WAIT4_BARRIER() do {                                                   \
    asm volatile("s_waitcnt vmcnt(4)" ::: "memory");                           \
    __builtin_amdgcn_sched_barrier(0);                                         \
    __builtin_amdgcn_s_barrier();                                              \
    __builtin_amdgcn_sched_barrier(0);                                         \
} while (0)

// Flat-grid tile decode with XCD grouping, 32 tiles per z (k_qkv_qk).
__device__ __forceinline__ void tile_decode(int bid, int nblk, int& z, int& mc) {
    int GBk = nblk >> 5;
    if ((GBk & 7) == 0) {
        z  = (bid & 7) + 8 * ((bid >> 3) >> 5);
        mc = (bid >> 3) & 31;
    } else {
        z  = bid >> 5;
        mc = bid & 31;
    }
}
// Same with 8 tiles per z (256-sq GEMMs).
__device__ __forceinline__ void tile_decode8(int bid, int nblk, int& z, int& mc) {
    int GBk = nblk >> 3;
    if ((GBk & 7) == 0) {
        z  = (bid & 7) + 8 * (bid >> 6);
        mc = (bid >> 3) & 7;
    } else {
        z  = bid >> 3;
        mc = bid & 7;
    }
}

// ---------------------------------------------------------------------------
// K0: dtype detector (even halfwords = fp32 low-mantissa garbage vs real bf16).
// ---------------------------------------------------------------------------
__global__ void k_detect(const unsigned short* __restrict__ xh, int* __restrict__ flag)
{
    __shared__ int red[256];
    int tid = threadIdx.x;
    unsigned short h = xh[2 * tid];
    int e = (h >> 7) & 0xFF;
    red[tid] = (e == 0 || (e >= 96 && e <= 159)) ? 1 : 0;
    __syncthreads();
    for (int s = 128; s > 0; s >>= 1) { if (tid < s) red[tid] += red[tid + s]; __syncthreads(); }
    if (tid == 0) *flag = (red[0] < 192) ? 1 : 0;
}

// ---------------------------------------------------------------------------
// K1a: spectral norm, phase 1: t = W^T u, split into 64-row chunks.
// ---------------------------------------------------------------------------
__global__ __launch_bounds__(256) void k_sn1(
    const void* __restrict__ Wq, const void* __restrict__ uq,
    const void* __restrict__ Wk, const void* __restrict__ uk,
    const void* __restrict__ Wv, const void* __restrict__ uv,
    const int* __restrict__ flag, float* __restrict__ tpart)
{
    __shared__ float sh_u[64];
    __shared__ float sh_acc[4][512];
    int f32 = *flag;
    int bx = blockIdx.x;
    const void *W, *u; int oc, slot;
    if (bx == 0)      { W = Wq; u = uq; oc = 0;      slot = 0; }
    else if (bx == 1) { W = Wk; u = uk; oc = 0;      slot = 1; }
    else              { W = Wv; u = uv; oc = bx - 2; slot = bx; }
    int tid = threadIdx.x, wave = tid >> 6, lane = tid & 63;
    if (tid < 64) sh_u[tid] = ldmix(u, oc * 64 + tid, f32);
    __syncthreads();

    float acc[8];
#pragma unroll
    for (int j = 0; j < 8; ++j) acc[j] = 0.f;
    int obase = oc * 64 + wave * 16;           // 16 contiguous rows per wave
#pragma unroll 4
    for (int i = 0; i < 16; ++i) {
        int o = obase + i;
        float w8[8]; ldvec8(W, (size_t)o * C_IN + lane * 8, f32, w8);
        float uo = sh_u[o - oc * 64];
#pragma unroll
        for (int j = 0; j < 8; ++j) acc[j] += w8[j] * uo;
    }
#pragma unroll
    for (int j = 0; j < 8; ++j) sh_acc[wave][lane * 8 + j] = acc[j];
    __syncthreads();
    for (int c = tid; c < 512; c += 256)
        tpart[(size_t)slot * 512 + c] =
            sh_acc[0][c] + sh_acc[1][c] + sh_acc[2][c] + sh_acc[3][c];
}

// ---------------------------------------------------------------------------
// K1b: spectral norm, phase 2. sig[m] = 1/sigma = sqrt(||t||^2 / ||W t||^2).
// ---------------------------------------------------------------------------
__global__ __launch_bounds__(512) void k_sn2(
    const void* __restrict__ Wq, const void* __restrict__ Wk,
    const void* __restrict__ Wv, const int* __restrict__ flag,
    const float* __restrict__ tpart, float* __restrict__ sig)
{
    __shared__ float sh_t[512];
    __shared__ float red[512];
    int f32 = *flag;
    int m = blockIdx.x;
    const void* W; int out, slot0, nch;
    if (m == 0)      { W = Wq; out = 64;  slot0 = 0; nch = 1; }
    else if (m == 1) { W = Wk; out = 64;  slot0 = 1; nch = 1; }
    else             { W = Wv; out = 512; slot0 = 2; nch = 8; }
    int tid = threadIdx.x, wave = tid >> 6, lane = tid & 63;

    float t = 0.f;
    for (int c2 = 0; c2 < nch; ++c2) t += tpart[(size_t)(slot0 + c2) * 512 + tid];
    sh_t[tid] = t;
    red[tid] = t * t;
    __syncthreads();
    for (int s = 256; s > 0; s >>= 1) { if (tid < s) red[tid] += red[tid + s]; __syncthreads(); }
    float t2 = red[0];
    __syncthreads();

    float tl[8];
#pragma unroll
    for (int j = 0; j < 8; ++j) tl[j] = sh_t[lane * 8 + j];

    float s2 = 0.f;
#pragma unroll 2
    for (int o = wave; o < out; o += 8) {
        float w8[8]; ldvec8(W, (size_t)o * C_IN + lane * 8, f32, w8);
        float d = 0.f;
#pragma unroll
        for (int j = 0; j < 8; ++j) d += w8[j] * tl[j];
#pragma unroll
        for (int off = 32; off > 0; off >>= 1) d += __shfl_xor(d, off);
        if (lane == 0) s2 += d * d;
    }
    __syncthreads();
    red[tid] = (lane == 0) ? s2 : 0.f;
    __syncthreads();
    for (int s = 256; s > 0; s >>= 1) { if (tid < s) red[tid] += red[tid + s]; __syncthreads(); }
    if (tid == 0) sig[m] = sqrtf(t2 / red[0]);
}

// ---------------------------------------------------------------------------
// K2: weight prep. Wb[640][512] = bf16(W * 1/sigma) stacked (q,k,v).
// ---------------------------------------------------------------------------
__global__ __launch_bounds__(256) void k_wscale(
    const void* __restrict__ Wq, const void* __restrict__ bq,
    const void* __restrict__ Wk, const void* __restrict__ bk,
    const void* __restrict__ Wv, const void* __restrict__ bv,
    const float* __restrict__ sig, const int* __restrict__ flag,
    bf16* __restrict__ Wb, bf16* __restrict__ Wlo, float* __restrict__ biasf)
{
    int f32 = *flag;
    int r = blockIdx.x;            // 0..639
    const void *W, *b; int row; float s;
    if (r < 64)       { W = Wq; b = bq; row = r;       s = sig[0]; }
    else if (r < 128) { W = Wk; b = bk; row = r - 64;  s = sig[1]; }
    else              { W = Wv; b = bv; row = r - 128; s = sig[2]; }
    for (int c = threadIdx.x; c < C_IN; c += 256) {
        float w = ldmix(W, (size_t)row * C_IN + c, f32) * s;
        bf16 hi = __float2bfloat16(w);
        Wb[(size_t)r * C_IN + c] = hi;
        if (r < 128)
            Wlo[(size_t)r * C_IN + c] = __float2bfloat16(w - __bfloat162float(hi));
    }
    if (threadIdx.x == 0) biasf[r] = ldmix(b, row, f32);
}

// ---------------------------------------------------------------------------
// K3: transpose x[c][n] -> xT[n][c] as split bf16 (hi @ +0, lo @ +1MB).
// ---------------------------------------------------------------------------
__global__ __launch_bounds__(256) void k_xt(
    const void* __restrict__ x, const int* __restrict__ flag,
    char* __restrict__ SX, int batch0)
{
    __shared__ float tile[64][65];
    int f32 = *flag;
    int z = blockIdx.z;
    int n0 = blockIdx.x * 64, c0 = blockIdx.y * 64;
    size_t xoff = (size_t)(batch0 + z) * C_IN * N_SP;
    bf16* xTh = (bf16*)(SX + (size_t)z * 4194304);
    bf16* xTl = xTh + 524288;
    int tid = threadIdx.x;
#pragma unroll
    for (int i = 0; i < 4; ++i) {
        int idx = tid + i * 256;           // 0..1023
        int c = idx >> 4, nq = idx & 15;
#pragma unroll
        for (int t = 0; t < 4; ++t)
            tile[c][nq * 4 + t] = ldmix(x, xoff + (size_t)(c0 + c) * N_SP + n0 + nq * 4 + t, f32);
    }
    __syncthreads();
#pragma unroll
    for (int i = 0; i < 16; ++i) {
        int idx = tid + i * 256;           // 0..4095
        int n = idx >> 6, c = idx & 63;
        float v = tile[c][n];
        bf16 hi = __float2bfloat16(v);
        xTh[(size_t)(n0 + n) * C_IN + c0 + c] = hi;
        xTl[(size_t)(n0 + n) * C_IN + c0 + c] = __float2bfloat16(v - __bfloat162float(hi));
    }
}

// ---------------------------------------------------------------------------
// K4: v-projection MFMA, 256x256 tile, BK=64, 8 waves, 4-phase counted
// schedule (vmcnt(4), never drained in-loop), 128 KB dynamic LDS.
// Yv[c][n] = sum_k Wb[128+c][k] * xT[n][k] + bias.
// ---------------------------------------------------------------------------
__global__ __launch_bounds__(512, 1) void k_qkv_v(
    const bf16* __restrict__ Wb, const float* __restrict__ biasf,
    const char* __restrict__ SX, bf16* __restrict__ YV)
{
    extern __shared__ char lds[];
    int z, mc; tile_decode8(blockIdx.x, gridDim.x, z, mc);
    int r0 = 128 + (mc >> 2) * 256;        // global W row (v band): 2 tiles
    int n0 = (mc & 3) * 256;               // 4 n-tiles
    const bf16* xTh = (const bf16*)(SX + (size_t)z * 4194304);
    bf16* Yv = YV + (size_t)z * 524288;
    int tid = threadIdx.x, wave = tid >> 6, lane = tid & 63, quad = lane >> 4, l16 = lane & 15;
    int wr = wave >> 2, wc4 = wave & 3;    // 2 row-groups x 4 col-groups

    const bf16* Ar = Wb + (size_t)r0 * C_IN;
    const bf16* Br = xTh + (size_t)n0 * C_IN;

    f32x4 acc[8][4];
#pragma unroll
    for (int i = 0; i < 8; ++i)
#pragma unroll
        for (int j = 0; j < 4; ++j) acc[i][j] = (f32x4){0.f, 0.f, 0.f, 0.f};

    STGUNIT(0, Ar, C_IN, Br, C_IN, 0);     // tile 0, kh 0
    STGUNIT(1, Ar, C_IN, Br, C_IN, 32);    // tile 0, kh 1

    const int NT = 8;                       // K = 512 = 8 x 64
    for (int t = 0; t < NT; ++t) {
        int d = t & 1;
#pragma unroll
        for (int kh = 0; kh < 2; ++kh) {
            const char* unit = lds + (size_t)(d * 2 + kh) * 32768;
            WAIT4_BARRIER();               // unit (t,kh) landed everywhere
            if (t + 1 < NT)
                STGUNIT((d ^ 1) * 2 + kh, Ar, C_IN, Br, C_IN, (t + 1) * 64 + kh * 32);
            bf16x8 bfr[4];
#pragma unroll
            for (int fn = 0; fn < 4; ++fn)
                bfr[fn] = frag32(unit + 16384, wc4 * 64 + fn * 16 + l16, quad);
            bf16x8 af[4];
#pragma unroll
            for (int fm = 0; fm < 4; ++fm)
                af[fm] = frag32(unit, wr * 128 + fm * 16 + l16, quad);
            __builtin_amdgcn_s_setprio(1);
#pragma unroll
            for (int fm = 0; fm < 4; ++fm)
#pragma unroll
                for (int fn = 0; fn < 4; ++fn)
                    acc[fm][fn] = __builtin_amdgcn_mfma_f32_16x16x32_bf16(af[fm], bfr[fn], acc[fm][fn], 0, 0, 0);
            __builtin_amdgcn_s_setprio(0);
#pragma unroll
            for (int fm = 0; fm < 4; ++fm)
                af[fm] = frag32(unit, wr * 128 + (fm + 4) * 16 + l16, quad);
            __builtin_amdgcn_s_setprio(1);
#pragma unroll
            for (int fm = 0; fm < 4; ++fm)
#pragma unroll
                for (int fn = 0; fn < 4; ++fn)
                    acc[fm + 4][fn] = __builtin_amdgcn_mfma_f32_16x16x32_bf16(af[fm], bfr[fn], acc[fm + 4][fn], 0, 0, 0);
            __builtin_amdgcn_s_setprio(0);
        }
    }

#pragma unroll
    for (int fm = 0; fm < 8; ++fm)
#pragma unroll
        for (int fn = 0; fn < 4; ++fn)
#pragma unroll
            for (int r = 0; r < 4; ++r) {
                int c = r0 + wr * 128 + fm * 16 + quad * 4 + r;   // global W row
                int n = n0 + wc4 * 64 + fn * 16 + l16;
                Yv[(size_t)(c - 128) * N_SP + n] = __float2bfloat16(acc[fm][fn][r] + biasf[c]);
            }
}

// ---------------------------------------------------------------------------
// K5: q/k projection, split-bf16 MFMA (AhBh + AhBl + AlBh ~ fp32 product).
// 64x64 tile, BK=32, global_load_lds staging, 3-buffer depth-2 pipeline.
// Output stored TRANSPOSED: qt/kt[n][o] (o fastest). (R4-verified.)
// ---------------------------------------------------------------------------
__global__ __launch_bounds__(256) void k_qkv_qk(
    const bf16* __restrict__ Wb, const bf16* __restrict__ Wlo,
    const float* __restrict__ biasf, const char* __restrict__ SX,
    bf16* __restrict__ QT, bf16* __restrict__ KT)
{
    __shared__ __bf16 Ah_[3][64][32], Al_[3][64][32], Bh_[3][64][32], Bl_[3][64][32];
    int z, mc; tile_decode(blockIdx.x, gridDim.x, z, mc);
    int n0 = (mc >> 1) * 64;
    int m0 = (mc & 1) * 64;                // 0 -> q rows, 64 -> k rows
    const bf16* xTh = (const bf16*)(SX + (size_t)z * 4194304);
    const bf16* xTl = xTh + 524288;
    bf16* qt = QT + (size_t)z * 65536;
    bf16* kt = KT + (size_t)z * 65536;
    int tid = threadIdx.x, wave = tid >> 6, lane = tid & 63, quad = lane >> 4, l16 = lane & 15;
    int wmh = (wave >> 1) * 32, wnh = (wave & 1) * 32;

    const bf16* Ahr = Wb  + (size_t)m0 * C_IN;
    const bf16* Alr = Wlo + (size_t)m0 * C_IN;
    const bf16* Bhr = xTh + (size_t)n0 * C_IN;
    const bf16* Blr = xTl + (size_t)n0 * C_IN;

    f32x4 acc[2][2];
#pragma unroll
    for (int i = 0; i < 2; ++i)
#pragma unroll
        for (int j = 0; j < 2; ++j) acc[i][j] = (f32x4){0.f, 0.f, 0.f, 0.f};

    STAGE64(Ah_[0], Ahr, C_IN, 0);  STAGE64(Al_[0], Alr, C_IN, 0);
    STAGE64(Bh_[0], Bhr, C_IN, 0);  STAGE64(Bl_[0], Blr, C_IN, 0);
    STAGE64(Ah_[1], Ahr, C_IN, 32); STAGE64(Al_[1], Alr, C_IN, 32);
    STAGE64(Bh_[1], Bhr, C_IN, 32); STAGE64(Bl_[1], Blr, C_IN, 32);
    char *ah0 = (char*)Ah_[0], *ah1 = (char*)Ah_[1], *ah2 = (char*)Ah_[2];
    char *al0 = (char*)Al_[0], *al1 = (char*)Al_[1], *al2 = (char*)Al_[2];
    char *bh0 = (char*)Bh_[0], *bh1 = (char*)Bh_[1], *bh2 = (char*)Bh_[2];
    char *bl0 = (char*)Bl_[0], *bl1 = (char*)Bl_[1], *bl2 = (char*)Bl_[2];

#define QK_MFMA(PAH, PAL, PBH, PBL) {                                          \
    bf16x8 fah[2], fal[2], fbh[2], fbl[2];                                     \
    _Pragma("unroll")                                                          \
    for (int i = 0; i < 2; ++i) {                                              \
        fah[i] = swz_frag(PAH, wmh + i * 16 + l16, quad);                      \
        fal[i] = swz_frag(PAL, wmh + i * 16 + l16, quad);                      \
    }                                                                          \
    _Pragma("unroll")                                                          \
    for (int j = 0; j < 2; ++j) {                                              \
        fbh[j] = swz_frag(PBH, wnh + j * 16 + l16, quad);                      \
        fbl[j] = swz_frag(PBL, wnh + j * 16 + l16, quad);                      \
    }                                                                          \
    __builtin_amdgcn_s_setprio(1);                                             \
    _Pragma("unroll")                                                          \
    for (int i = 0; i < 2; ++i)                                                \
        _Pragma("unroll")                                                      \
        for (int j = 0; j < 2; ++j) {                                          \
            acc[i][j] = __builtin_amdgcn_mfma_f32_16x16x32_bf16(fah[i], fbh[j], acc[i][j], 0, 0, 0); \
            acc[i][j] = __builtin_amdgcn_mfma_f32_16x16x32_bf16(fah[i], fbl[j], acc[i][j], 0, 0, 0); \
            acc[i][j] = __builtin_amdgcn_mfma_f32_16x16x32_bf16(fal[i], fbh[j], acc[i][j], 0, 0, 0); \
        }                                                                      \
    __builtin_amdgcn_s_setprio(0); }

    for (int t = 0; t < 15; ++t) {
        asm volatile("s_waitcnt vmcnt(4)" ::: "memory");
        __builtin_amdgcn_s_barrier();
        __builtin_amdgcn_sched_barrier(0);
        if (t + 2 < 16) {
            int k2 = (t + 2) * 32;
            STAGE64(ah2, Ahr, C_IN, k2); STAGE64(al2, Alr, C_IN, k2);
            STAGE64(bh2, Bhr, C_IN, k2); STAGE64(bl2, Blr, C_IN, k2);
        }
        QK_MFMA(ah0, al0, bh0, bl0);
        char* tp = ah0; ah0 = ah1; ah1 = ah2; ah2 = tp;
        tp = al0; al0 = al1; al1 = al2; al2 = tp;
        tp = bh0; bh0 = bh1; bh1 = bh2; bh2 = tp;
        tp = bl0; bl0 = bl1; bl1 = bl2; bl2 = tp;
    }
    asm volatile("s_waitcnt vmcnt(0)" ::: "memory");
    __builtin_amdgcn_s_barrier();
    __builtin_amdgcn_sched_barrier(0);
    QK_MFMA(ah0, al0, bh0, bl0);
#undef QK_MFMA

#pragma unroll
    for (int i = 0; i < 2; ++i)
#pragma unroll
        for (int j = 0; j < 2; ++j) {
            int cbase = m0 + wmh + i * 16 + quad * 4;       // global row, +r (4 consecutive)
            int n = n0 + wnh + j * 16 + l16;
            ushort4 st;
            st.x = bfbits(acc[i][j][0] + biasf[cbase + 0]);
            st.y = bfbits(acc[i][j][1] + biasf[cbase + 1]);
            st.z = bfbits(acc[i][j][2] + biasf[cbase + 2]);
            st.w = bfbits(acc[i][j][3] + biasf[cbase + 3]);
            bf16* dst = (m0 == 0) ? &qt[(size_t)n * 64 + cbase]
                                  : &kt[(size_t)n * 64 + (cbase - 64)];
            *reinterpret_cast<ushort4*>(dst) = st;           // 8 B, aligned
        }
}

// ---------------------------------------------------------------------------
// K6: scores MFMA. S[m][n] = sum_o kt[m][o] * qt[n][o], fp32 out (over dead xT).
// 128x128 tile, K=64 (2 x BK=32), 4 waves x 4x4. (K too short to pipeline.)
// ---------------------------------------------------------------------------
__global__ __launch_bounds__(256) void k_qk(
    const bf16* __restrict__ QT, const bf16* __restrict__ KT,
    char* __restrict__ SX)
{
    __shared__ __bf16 Als[128][40];
    __shared__ __bf16 Bls[128][40];
    int z = blockIdx.z, m0 = blockIdx.y * 128, n0 = blockIdx.x * 128;
    const bf16* qt = QT + (size_t)z * 65536;
    const bf16* kt = KT + (size_t)z * 65536;
    float* Sf = (float*)(SX + (size_t)z * 4194304);
    int tid = threadIdx.x, wave = tid >> 6, lane = tid & 63, quad = lane >> 4, l16 = lane & 15;
    int wc = (wave >> 1) * 64, wm = (wave & 1) * 64;

    f32x4 acc[4][4];
#pragma unroll
    for (int i = 0; i < 4; ++i)
#pragma unroll
        for (int j = 0; j < 4; ++j) acc[i][j] = (f32x4){0.f, 0.f, 0.f, 0.f};

#pragma unroll
    for (int k0 = 0; k0 < 64; k0 += 32) {
#pragma unroll
        for (int s = 0; s < 2; ++s) {
            int idx = tid + s * 256; int row = idx >> 2, ch = idx & 3;
            *reinterpret_cast<uint4*>(&Als[row][ch * 8]) =
                *reinterpret_cast<const uint4*>(&kt[(size_t)(m0 + row) * 64 + k0 + ch * 8]);
            *reinterpret_cast<uint4*>(&Bls[row][ch * 8]) =
                *reinterpret_cast<const uint4*>(&qt[(size_t)(n0 + row) * 64 + k0 + ch * 8]);
        }
        __syncthreads();
        bf16x8 a[4], b[4];
#pragma unroll
        for (int i = 0; i < 4; ++i)
            a[i] = *reinterpret_cast<const bf16x8*>(&Als[wc + i * 16 + l16][quad * 8]);
#pragma unroll
        for (int j = 0; j < 4; ++j)
            b[j] = *reinterpret_cast<const bf16x8*>(&Bls[wm + j * 16 + l16][quad * 8]);
#pragma unroll
        for (int i = 0; i < 4; ++i)
#pragma unroll
            for (int j = 0; j < 4; ++j)
                acc[i][j] = __builtin_amdgcn_mfma_f32_16x16x32_bf16(a[i], b[j], acc[i][j], 0, 0, 0);
        __syncthreads();
    }
#pragma unroll
    for (int i = 0; i < 4; ++i)
#pragma unroll
        for (int j = 0; j < 4; ++j)
#pragma unroll
            for (int r = 0; r < 4; ++r) {
                int m = m0 + wc + i * 16 + quad * 4 + r;
                int n = n0 + wm + j * 16 + l16;
                Sf[(size_t)m * N_SP + n] = acc[i][j][r];
            }
}

// ---------------------------------------------------------------------------
// K7: row softmax, fp32 in -> bf16 P written IN PLACE (row owned by block).
// ---------------------------------------------------------------------------
__global__ __launch_bounds__(256) void k_softmax(char* __restrict__ SX)
{
    __shared__ float red[256];
    int z = blockIdx.x >> 10, m = blockIdx.x & 1023;
    float* p = (float*)(SX + (size_t)z * 4194304) + (size_t)m * N_SP;
    bf16* pb = (bf16*)p;
    int tid = threadIdx.x;
    float v0 = p[tid], v1 = p[tid + 256], v2 = p[tid + 512], v3 = p[tid + 768];
    red[tid] = fmaxf(fmaxf(v0, v1), fmaxf(v2, v3));
    __syncthreads();
    for (int s = 128; s > 0; s >>= 1) { if (tid < s) red[tid] = fmaxf(red[tid], red[tid + s]); __syncthreads(); }
    float mx = red[0];
    __syncthreads();
    float d0 = fmaxf(fminf(v0 - mx, 0.f), -80.f);
    float d1 = fmaxf(fminf(v1 - mx, 0.f), -80.f);
    float d2 = fmaxf(fminf(v2 - mx, 0.f), -80.f);
    float d3 = fmaxf(fminf(v3 - mx, 0.f), -80.f);
    float e0 = __expf(d0), e1 = __expf(d1), e2 = __expf(d2), e3 = __expf(d3);
    red[tid] = e0 + e1 + e2 + e3;
    __syncthreads();
    for (int s = 128; s > 0; s >>= 1) { if (tid < s) red[tid] += red[tid + s]; __syncthreads(); }
    float inv = 1.f / red[0];
    pb[tid]       = __float2bfloat16(e0 * inv);
    pb[tid + 256] = __float2bfloat16(e1 * inv);
    pb[tid + 512] = __float2bfloat16(e2 * inv);
    pb[tid + 768] = __float2bfloat16(e3 * inv);
}

// ---------------------------------------------------------------------------
// K8: output MFMA, 256x256 tile, BK=64, 8 waves, 4-phase counted schedule
// (vmcnt(4), never drained in-loop), 128 KB dynamic LDS.
// out[c][m] = gamma * sum_n Yv[c][n]*P[m][n] + x[c][m]. P pitch 2048 bf16.
// ---------------------------------------------------------------------------
__global__ __launch_bounds__(512, 1) void k_out(
    const bf16* __restrict__ YV, const char* __restrict__ SX,
    const void* __restrict__ x, const void* __restrict__ gamma,
    const int* __restrict__ flag, void* __restrict__ out, int batch0)
{
    extern __shared__ char lds[];
    int f32 = *flag;
    int z, mc; tile_decode8(blockIdx.x, gridDim.x, z, mc);
    int c0 = (mc >> 2) * 256;              // 2 c-tiles
    int m0 = (mc & 3) * 256;               // 4 m-tiles
    const bf16* Yv = YV + (size_t)z * 524288;
    const bf16* Pb = (const bf16*)(SX + (size_t)z * 4194304);   // pitch 2048
    int tid = threadIdx.x, wave = tid >> 6, lane = tid & 63, quad = lane >> 4, l16 = lane & 15;
    int wr = wave >> 2, wc4 = wave & 3;

    const bf16* Ar = Yv + (size_t)c0 * N_SP;
    const bf16* Br = Pb + (size_t)m0 * 2048;

    f32x4 acc[8][4];
#pragma unroll
    for (int i = 0; i < 8; ++i)
#pragma unroll
        for (int j = 0; j < 4; ++j) acc[i][j] = (f32x4){0.f, 0.f, 0.f, 0.f};

    STGUNIT(0, Ar, N_SP, Br, 2048, 0);     // tile 0, kh 0
    STGUNIT(1, Ar, N_SP, Br, 2048, 32);    // tile 0, kh 1

    const int NT = 16;                      // K = 1024 = 16 x 64
    for (int t = 0; t < NT; ++t) {
        int d = t & 1;
#pragma unroll
        for (int kh = 0; kh < 2; ++kh) {
            const char* unit = lds + (size_t)(d * 2 + kh) * 32768;
            WAIT4_BARRIER();               // unit (t,kh) landed everywhere
            if (t + 1 < NT)
                STGUNIT((d ^ 1) * 2 + kh, Ar, N_SP, Br, 2048, (t + 1) * 64 + kh * 32);
            bf16x8 bfr[4];
#pragma unroll
            for (int fn = 0; fn < 4; ++fn)
                bfr[fn] = frag32(unit + 16384, wc4 * 64 + fn * 16 + l16, quad);
            bf16x8 af[4];
#pragma unroll
            for (int fm = 0; fm < 4; ++fm)
                af[fm] = frag32(unit, wr * 128 + fm * 16 + l16, quad);
            __builtin_amdgcn_s_setprio(1);
#pragma unroll
            for (int fm = 0; fm < 4; ++fm)
#pragma unroll
                for (int fn = 0; fn < 4; ++fn)
                    acc[fm][fn] = __builtin_amdgcn_mfma_f32_16x16x32_bf16(af[fm], bfr[fn], acc[fm][fn], 0, 0, 0);
            __builtin_amdgcn_s_setprio(0);
#pragma unroll
            for (int fm = 0; fm < 4; ++fm)
                af[fm] = frag32(unit, wr * 128 + (fm + 4) * 16 + l16, quad);
            __builtin_amdgcn_s_setprio(1);
#pragma unroll
            for (int fm = 0; fm < 4; ++fm)
#pragma unroll
                for (int fn = 0; fn < 4; ++fn)
                    acc[fm + 4][fn] = __builtin_amdgcn_mfma_f32_16x16x32_bf16(af[fm], bfr[fn], acc[fm + 4][fn], 0, 0, 0);
            __builtin_amdgcn_s_setprio(0);
        }
    }

    float g = ldmix(gamma, 0, f32);
    const size_t base = (size_t)(batch0 + z) * C_IN * N_SP;
#pragma unroll
    for (int fm = 0; fm < 8; ++fm)
#pragma unroll
        for (int fn = 0; fn < 4; ++fn)
#pragma unroll
            for (int r = 0; r < 4; ++r) {
                int c = c0 + wr * 128 + fm * 16 + quad * 4 + r;
                int m = m0 + wc4 * 64 + fn * 16 + l16;
                size_t o = base + (size_t)c * N_SP + m;
                float v = fmaf(g, acc[fm][fn][r], ldmix(x, o, f32));
                if (!(v == v)) v = 5555.0f + 1000.0f * f32;   // NaN sentinel
                stmix(out, o, v, f32);
            }
}

// Diagnostic: workspace too small even for GB=1.
__global__ void k_wsfail(float* __restrict__ out, int n)
{
    int i = blockIdx.x * 256 + threadIdx.x;
    if (i < n) out[i] = 7777.0f;
}

// ---------------------------------------------------------------------------
extern "C" void kernel_launch(void* const* d_in, const int* in_sizes, int n_in,
                              void* d_out, int out_size, void* d_ws, size_t ws_size,
                              hipStream_t stream)
{
    const void* x  = d_in[0];
    const void* Wq = d_in[1];
    const void* bq = d_in[2];
    const void* Wk = d_in[4];
    const void* bk = d_in[5];
    const void* Wv = d_in[7];
    const void* bv = d_in[8];
    const void* uq = d_in[3];
    const void* uk = d_in[6];
    const void* uv = d_in[9];
    const void* gm = d_in[10];

    // Allow 128 KB dynamic LDS for the 256-sq GEMMs (defensive; ignore errors).
    static int lds_opt_done = 0;
    if (!lds_opt_done) {
        (void)hipFuncSetAttribute(reinterpret_cast<const void*>(k_qkv_v),
                                  hipFuncAttributeMaxDynamicSharedMemorySize, 131072);
        (void)hipFuncSetAttribute(reinterpret_cast<const void*>(k_out),
                                  hipFuncAttributeMaxDynamicSharedMemorySize, 131072);
        lds_opt_done = 1;
    }

    // ws layout:
    //   flag @0, sig[3] @16, biasf[640] @256, Wb bf16[640][512] @4096,
    //   Wlo bf16[128][512] @659456 -> group region @790528:
    //     SX: GB x 4MB  (xT_hi 1MB | xT_lo 1MB | ...), later fp32 S overwrites
    //     QT: GB x 128KB, KT: GB x 128KB, YV: GB x 1MB
    //   tpart (spectral partials) aliases the head of SX (dead before k_xt).
    const size_t HDR = 790528;
    const size_t per = 4194304 + 131072 + 131072 + 1048576;   // 5,505,024
    int GB = 0;
    for (int g = 32; g >= 1; g >>= 1)
        if (HDR + (size_t)g * per <= ws_size) { GB = g; break; }
    if (GB == 0) {
        k_wsfail<<<(out_size + 255) / 256, 256, 0, stream>>>((float*)d_out, out_size);
        return;
    }
    char* ws = (char*)d_ws;
    int*   flag  = (int*)ws;
    float* sig   = (float*)(ws + 16);
    float* biasf = (float*)(ws + 256);
    bf16*  Wb    = (bf16*)(ws + 4096);
    bf16*  Wlo   = (bf16*)(ws + 659456);
    char*  SX    = ws + HDR;
    bf16*  QT    = (bf16*)(SX + (size_t)GB * 4194304);
    bf16*  KT    = QT + (size_t)GB * 65536;
    bf16*  YV    = KT + (size_t)GB * 65536;
    float* tpart = (float*)SX;    // dead before first k_xt write

    k_detect<<<1, 256, 0, stream>>>((const unsigned short*)x, flag);
    k_sn1<<<10, 256, 0, stream>>>(Wq, uq, Wk, uk, Wv, uv, flag, tpart);
    k_sn2<<<3, 512, 0, stream>>>(Wq, Wk, Wv, flag, tpart, sig);
    k_wscale<<<640, 256, 0, stream>>>(Wq, bq, Wk, bk, Wv, bv, sig, flag, Wb, Wlo, biasf);
    for (int b0 = 0; b0 < BATCH; b0 += GB) {
        k_xt     <<<dim3(16, 8, GB), 256, 0, stream>>>(x, flag, SX, b0);
        k_qkv_v  <<<GB * 8, 512, 131072, stream>>>(Wb, biasf, SX, YV);
        k_qkv_qk <<<GB * 32, 256, 0, stream>>>(Wb, Wlo, biasf, SX, QT, KT);
        k_qk     <<<dim3(8, 8, GB), 256, 0, stream>>>(QT, KT, SX);
        k_softmax<<<GB * 1024, 256, 0, stream>>>(SX);
        k_out    <<<GB * 8, 512, 131072, stream>>>(YV, SX, x, gm, flag, d_out, b0);
    }
}

// Round 7
// 387.927 us; speedup vs baseline: 1.0227x; 1.0227x over previous
//
#include <hip/hip_runtime.h>
#include <hip/hip_bf16.h>

typedef __hip_bfloat16 bf16;
typedef __bf16 bf16x8 __attribute__((ext_vector_type(8)));
typedef float  f32x4  __attribute__((ext_vector_type(4)));
typedef unsigned short u16x8 __attribute__((ext_vector_type(8)));

#define C_IN  512
#define N_SP  1024
#define BATCH 32

// Mixed-dtype accessors: f32 flag selects fp32 or bf16 view of the SAME buffer.
__device__ __forceinline__ float ldmix(const void* p, size_t i, int f32) {
    return f32 ? ((const float*)p)[i] : __bfloat162float(((const bf16*)p)[i]);
}
__device__ __forceinline__ void stmix(void* p, size_t i, float v, int f32) {
    if (f32) ((float*)p)[i] = v;
    else     ((bf16*)p)[i] = __float2bfloat16(v);
}
__device__ __forceinline__ unsigned short bfbits(float f) {
    bf16 t = __float2bfloat16(f);
    return *reinterpret_cast<unsigned short*>(&t);
}
__device__ __forceinline__ float bf2f(unsigned short h) {
    union { unsigned u; float f; } c; c.u = ((unsigned)h) << 16; return c.f;
}
// 8 consecutive elements of W starting at element index `base` (base % 8 == 0).
__device__ __forceinline__ void ldvec8(const void* W, size_t base, int f32, float v[8]) {
    if (f32) {
        const float4* p = reinterpret_cast<const float4*>((const float*)W + base);
        float4 a = p[0], b = p[1];
        v[0] = a.x; v[1] = a.y; v[2] = a.z; v[3] = a.w;
        v[4] = b.x; v[5] = b.y; v[6] = b.z; v[7] = b.w;
    } else {
        u16x8 h = *reinterpret_cast<const u16x8*>((const bf16*)W + base);
#pragma unroll
        for (int j = 0; j < 8; ++j) v[j] = bf2f(h[j]);
    }
}

// ---------------------------------------------------------------------------
// Async global->LDS staging (gfx950). LDS dest = wave-uniform base + lane*16
// (linear). Swizzled LDS layout achieved by pre-swizzling the per-lane GLOBAL
// source; the ds_read applies the same XOR (both-sides-or-neither, rule #21).
// Swizzle: 16B chunk s of row r stored at chunk s ^ ((r>>1)&3) (4 chunks/row,
// 64B rows). Measured conflict-free (SQ_LDS_BANK_CONFLICT = 0, R5/R6).
// ---------------------------------------------------------------------------
__device__ __forceinline__ void gload_lds16(const bf16* g, void* l) {
    __builtin_amdgcn_global_load_lds(
        (__attribute__((address_space(1))) void*)(g),
        (__attribute__((address_space(3))) void*)(l),
        16, 0, 0);
}

// --- BK=32 staging (64-row tile), used by k_qkv_qk (R4-verified) -----------
#define STAGE64(LDS, GROW, GPITCH, K0) do {                                    \
    int _c = (wave << 6) + lane; int _r = _c >> 2;                             \
    int _s = (_c & 3) ^ ((_r >> 1) & 3);                                       \
    gload_lds16((GROW) + (size_t)_r * (GPITCH) + (K0) + _s * 8,                \
                (char*)(LDS) + (wave << 10));                                  \
} while (0)

__device__ __forceinline__ bf16x8 swz_frag(const void* tile, int row, int quad) {
    return *(const bf16x8*)((const char*)tile + (row << 6) +
                            ((quad ^ ((row >> 1) & 3)) << 4));
}

// --- 128x256 GEMM unit staging: A[128][32] (8 KB) + B[256][32] (16 KB) -----
// One unit = 24 KB, 3 gload_lds per wave (1 A + 2 B). 3 units = 72 KB LDS
// -> 2 blocks/CU (the R6 post-mortem lever: cross-block overlap).
#define STGU(UB, AROW, APITCH, BROW, BPITCH, KOFF) do {                        \
    { int _c = (wave << 6) + lane; int _r = _c >> 2;                           \
      int _s = (_c & 3) ^ ((_r >> 1) & 3);                                     \
      gload_lds16((AROW) + (size_t)_r * (APITCH) + (KOFF) + _s * 8,            \
                  (char*)(UB) + (wave << 10)); }                               \
    _Pragma("unroll")                                                          \
    for (int _i = 0; _i < 2; ++_i) {                                           \
        int _c = ((wave * 2 + _i) << 6) + lane; int _r = _c >> 2;              \
        int _s = (_c & 3) ^ ((_r >> 1) & 3);                                   \
        gload_lds16((BROW) + (size_t)_r * (BPITCH) + (KOFF) + _s * 8,          \
                    (char*)(UB) + 8192 + ((wave * 2 + _i) << 10));             \
    }                                                                          \
} while (0)

__device__ __forceinline__ bf16x8 frag32(const char* part, int row, int quad) {
    return *(const bf16x8*)(part + (row << 6) +
                            ((quad ^ ((row >> 1) & 3)) << 4));
}

#define WAITN_BARRIER(N) do {                                                  \
    asm volatile("s_waitcnt vmcnt(" #N ")" ::: "memory");                      \
    __builtin_amdgcn_sched_barrier(0);                                         \
    __builtin_amdgcn_s_barrier();                                              \
    __builtin_amdgcn_sched_barrier(0);                                         \
} while (0)

// Flat-grid tile decode with XCD grouping, 32 tiles per z (k_qkv_qk).
__device__ __forceinline__ void tile_decode(int bid, int nblk, int& z, int& mc) {
    int GBk = nblk >> 5;
    if ((GBk & 7) == 0) {
        z  = (bid & 7) + 8 * ((bid >> 3) >> 5);
        mc = (bid >> 3) & 31;
    } else {
        z  = bid >> 5;
        mc = bid & 31;
    }
}
// Same with 16 tiles per z (128x256 GEMMs). Bijective for nblk = GB*16, GB%8==0.
__device__ __forceinline__ void tile_decode16(int bid, int nblk, int& z, int& mc) {
    int GBk = nblk >> 4;
    if ((GBk & 7) == 0) {
        z  = (bid & 7) + 8 * (bid >> 7);
        mc = (bid >> 3) & 15;
    } else {
        z  = bid >> 4;
        mc = bid & 15;
    }
}

// ---------------------------------------------------------------------------
// K0: dtype detector (even halfwords = fp32 low-mantissa garbage vs real bf16).
// ---------------------------------------------------------------------------
__global__ void k_detect(const unsigned short* __restrict__ xh, int* __restrict__ flag)
{
    __shared__ int red[256];
    int tid = threadIdx.x;
    unsigned short h = xh[2 * tid];
    int e = (h >> 7) & 0xFF;
    red[tid] = (e == 0 || (e >= 96 && e <= 159)) ? 1 : 0;
    __syncthreads();
    for (int s = 128; s > 0; s >>= 1) { if (tid < s) red[tid] += red[tid + s]; __syncthreads(); }
    if (tid == 0) *flag = (red[0] < 192) ? 1 : 0;
}

// ---------------------------------------------------------------------------
// K1a: spectral norm, phase 1: t = W^T u, split into 64-row chunks.
// ---------------------------------------------------------------------------
__global__ __launch_bounds__(256) void k_sn1(
    const void* __restrict__ Wq, const void* __restrict__ uq,
    const void* __restrict__ Wk, const void* __restrict__ uk,
    const void* __restrict__ Wv, const void* __restrict__ uv,
    const int* __restrict__ flag, float* __restrict__ tpart)
{
    __shared__ float sh_u[64];
    __shared__ float sh_acc[4][512];
    int f32 = *flag;
    int bx = blockIdx.x;
    const void *W, *u; int oc, slot;
    if (bx == 0)      { W = Wq; u = uq; oc = 0;      slot = 0; }
    else if (bx == 1) { W = Wk; u = uk; oc = 0;      slot = 1; }
    else              { W = Wv; u = uv; oc = bx - 2; slot = bx; }
    int tid = threadIdx.x, wave = tid >> 6, lane = tid & 63;
    if (tid < 64) sh_u[tid] = ldmix(u, oc * 64 + tid, f32);
    __syncthreads();

    float acc[8];
#pragma unroll
    for (int j = 0; j < 8; ++j) acc[j] = 0.f;
    int obase = oc * 64 + wave * 16;           // 16 contiguous rows per wave
#pragma unroll 4
    for (int i = 0; i < 16; ++i) {
        int o = obase + i;
        float w8[8]; ldvec8(W, (size_t)o * C_IN + lane * 8, f32, w8);
        float uo = sh_u[o - oc * 64];
#pragma unroll
        for (int j = 0; j < 8; ++j) acc[j] += w8[j] * uo;
    }
#pragma unroll
    for (int j = 0; j < 8; ++j) sh_acc[wave][lane * 8 + j] = acc[j];
    __syncthreads();
    for (int c = tid; c < 512; c += 256)
        tpart[(size_t)slot * 512 + c] =
            sh_acc[0][c] + sh_acc[1][c] + sh_acc[2][c] + sh_acc[3][c];
}

// ---------------------------------------------------------------------------
// K1b: spectral norm, phase 2. sig[m] = 1/sigma = sqrt(||t||^2 / ||W t||^2).
// ---------------------------------------------------------------------------
__global__ __launch_bounds__(512) void k_sn2(
    const void* __restrict__ Wq, const void* __restrict__ Wk,
    const void* __restrict__ Wv, const int* __restrict__ flag,
    const float* __restrict__ tpart, float* __restrict__ sig)
{
    __shared__ float sh_t[512];
    __shared__ float red[512];
    int f32 = *flag;
    int m = blockIdx.x;
    const void* W; int out, slot0, nch;
    if (m == 0)      { W = Wq; out = 64;  slot0 = 0; nch = 1; }
    else if (m == 1) { W = Wk; out = 64;  slot0 = 1; nch = 1; }
    else             { W = Wv; out = 512; slot0 = 2; nch = 8; }
    int tid = threadIdx.x, wave = tid >> 6, lane = tid & 63;

    float t = 0.f;
    for (int c2 = 0; c2 < nch; ++c2) t += tpart[(size_t)(slot0 + c2) * 512 + tid];
    sh_t[tid] = t;
    red[tid] = t * t;
    __syncthreads();
    for (int s = 256; s > 0; s >>= 1) { if (tid < s) red[tid] += red[tid + s]; __syncthreads(); }
    float t2 = red[0];
    __syncthreads();

    float tl[8];
#pragma unroll
    for (int j = 0; j < 8; ++j) tl[j] = sh_t[lane * 8 + j];

    float s2 = 0.f;
#pragma unroll 2
    for (int o = wave; o < out; o += 8) {
        float w8[8]; ldvec8(W, (size_t)o * C_IN + lane * 8, f32, w8);
        float d = 0.f;
#pragma unroll
        for (int j = 0; j < 8; ++j) d += w8[j] * tl[j];
#pragma unroll
        for (int off = 32; off > 0; off >>= 1) d += __shfl_xor(d, off);
        if (lane == 0) s2 += d * d;
    }
    __syncthreads();
    red[tid] = (lane == 0) ? s2 : 0.f;
    __syncthreads();
    for (int s = 256; s > 0; s >>= 1) { if (tid < s) red[tid] += red[tid + s]; __syncthreads(); }
    if (tid == 0) sig[m] = sqrtf(t2 / red[0]);
}

// ---------------------------------------------------------------------------
// K2: weight prep. Wb[640][512] = bf16(W * 1/sigma) stacked (q,k,v).
// ---------------------------------------------------------------------------
__global__ __launch_bounds__(256) void k_wscale(
    const void* __restrict__ Wq, const void* __restrict__ bq,
    const void* __restrict__ Wk, const void* __restrict__ bk,
    const void* __restrict__ Wv, const void* __restrict__ bv,
    const float* __restrict__ sig, const int* __restrict__ flag,
    bf16* __restrict__ Wb, bf16* __restrict__ Wlo, float* __restrict__ biasf)
{
    int f32 = *flag;
    int r = blockIdx.x;            // 0..639
    const void *W, *b; int row; float s;
    if (r < 64)       { W = Wq; b = bq; row = r;       s = sig[0]; }
    else if (r < 128) { W = Wk; b = bk; row = r - 64;  s = sig[1]; }
    else              { W = Wv; b = bv; row = r - 128; s = sig[2]; }
    for (int c = threadIdx.x; c < C_IN; c += 256) {
        float w = ldmix(W, (size_t)row * C_IN + c, f32) * s;
        bf16 hi = __float2bfloat16(w);
        Wb[(size_t)r * C_IN + c] = hi;
        if (r < 128)
            Wlo[(size_t)r * C_IN + c] = __float2bfloat16(w - __bfloat162float(hi));
    }
    if (threadIdx.x == 0) biasf[r] = ldmix(b, row, f32);
}

// ---------------------------------------------------------------------------
// K3: transpose x[c][n] -> xT[n][c] as split bf16 (hi @ +0, lo @ +1MB).
// ---------------------------------------------------------------------------
__global__ __launch_bounds__(256) void k_xt(
    const void* __restrict__ x, const int* __restrict__ flag,
    char* __restrict__ SX, int batch0)
{
    __shared__ float tile[64][65];
    int f32 = *flag;
    int z = blockIdx.z;
    int n0 = blockIdx.x * 64, c0 = blockIdx.y * 64;
    size_t xoff = (size_t)(batch0 + z) * C_IN * N_SP;
    bf16* xTh = (bf16*)(SX + (size_t)z * 4194304);
    bf16* xTl = xTh + 524288;
    int tid = threadIdx.x;
#pragma unroll
    for (int i = 0; i < 4; ++i) {
        int idx = tid + i * 256;           // 0..1023
        int c = idx >> 4, nq = idx & 15;
#pragma unroll
        for (int t = 0; t < 4; ++t)
            tile[c][nq * 4 + t] = ldmix(x, xoff + (size_t)(c0 + c) * N_SP + n0 + nq * 4 + t, f32);
    }
    __syncthreads();
#pragma unroll
    for (int i = 0; i < 16; ++i) {
        int idx = tid + i * 256;           // 0..4095
        int n = idx >> 6, c = idx & 63;
        float v = tile[c][n];
        bf16 hi = __float2bfloat16(v);
        xTh[(size_t)(n0 + n) * C_IN + c0 + c] = hi;
        xTl[(size_t)(n0 + n) * C_IN + c0 + c] = __float2bfloat16(v - __bfloat162float(hi));
    }
}

// ---------------------------------------------------------------------------
// K4: v-projection MFMA, 128x256 tile, BK=32, 8 waves (2x4), 3-buffer depth-2
// counted pipeline, 72 KB dynamic LDS -> 2 blocks/CU (cross-block overlap).
// Yv[c][n] = sum_k Wb[128+c][k] * xT[n][k] + bias.
// ---------------------------------------------------------------------------
__global__ __launch_bounds__(512, 4) void k_qkv_v(
    const bf16* __restrict__ Wb, const float* __restrict__ biasf,
    const char* __restrict__ SX, bf16* __restrict__ YV)
{
    extern __shared__ char lds[];
    int z, mc; tile_decode16(blockIdx.x, gridDim.x, z, mc);
    int r0 = 128 + (mc >> 2) * 128;        // global W row (v band): 4 tiles of 128
    int n0 = (mc & 3) * 256;               // 4 n-tiles of 256
    const bf16* xTh = (const bf16*)(SX + (size_t)z * 4194304);
    bf16* Yv = YV + (size_t)z * 524288;
    int tid = threadIdx.x, wave = tid >> 6, lane = tid & 63, quad = lane >> 4, l16 = lane & 15;
    int wr = wave >> 2, wc4 = wave & 3;    // 2 row-groups (64) x 4 col-groups (64)

    const bf16* Ar = Wb + (size_t)r0 * C_IN;
    const bf16* Br = xTh + (size_t)n0 * C_IN;

    f32x4 acc[4][4];
#pragma unroll
    for (int i = 0; i < 4; ++i)
#pragma unroll
        for (int j = 0; j < 4; ++j) acc[i][j] = (f32x4){0.f, 0.f, 0.f, 0.f};

    STGU(lds,         Ar, C_IN, Br, C_IN, 0);
    STGU(lds + 24576, Ar, C_IN, Br, C_IN, 32);

#define VG_MFMA(UB) {                                                          \
    bf16x8 af[4], bfr[4];                                                      \
    _Pragma("unroll")                                                          \
    for (int fm = 0; fm < 4; ++fm)                                             \
        af[fm] = frag32(UB, wr * 64 + fm * 16 + l16, quad);                    \
    _Pragma("unroll")                                                          \
    for (int fn = 0; fn < 4; ++fn)                                             \
        bfr[fn] = frag32((UB) + 8192, wc4 * 64 + fn * 16 + l16, quad);         \
    __builtin_amdgcn_s_setprio(1);                                             \
    _Pragma("unroll")                                                          \
    for (int fm = 0; fm < 4; ++fm)                                             \
        _Pragma("unroll")                                                      \
        for (int fn = 0; fn < 4; ++fn)                                         \
            acc[fm][fn] = __builtin_amdgcn_mfma_f32_16x16x32_bf16(af[fm], bfr[fn], acc[fm][fn], 0, 0, 0); \
    __builtin_amdgcn_s_setprio(0); }

    const int NT = 16;                      // K = 512 = 16 x 32
    int bsel = 0;
    for (int t = 0; t < NT - 1; ++t) {
        WAITN_BARRIER(3);                  // unit t landed block-wide
        if (t + 2 < NT) {
            int nb = bsel + 2; if (nb >= 3) nb -= 3;
            STGU(lds + (size_t)nb * 24576, Ar, C_IN, Br, C_IN, (t + 2) * 32);
        }
        VG_MFMA(lds + (size_t)bsel * 24576);
        if (++bsel == 3) bsel = 0;
    }
    WAITN_BARRIER(0);
    VG_MFMA(lds + (size_t)bsel * 24576);
#undef VG_MFMA

#pragma unroll
    for (int fm = 0; fm < 4; ++fm)
#pragma unroll
        for (int fn = 0; fn < 4; ++fn)
#pragma unroll
            for (int r = 0; r < 4; ++r) {
                int c = r0 + wr * 64 + fm * 16 + quad * 4 + r;    // global W row
                int n = n0 + wc4 * 64 + fn * 16 + l16;
                Yv[(size_t)(c - 128) * N_SP + n] = __float2bfloat16(acc[fm][fn][r] + biasf[c]);
            }
}

// ---------------------------------------------------------------------------
// K5: q/k projection, split-bf16 MFMA (AhBh + AhBl + AlBh ~ fp32 product).
// 64x64 tile, BK=32, global_load_lds staging, 3-buffer depth-2 pipeline.
// Output stored TRANSPOSED: qt/kt[n][o] (o fastest). (R4-verified.)
// ---------------------------------------------------------------------------
__global__ __launch_bounds__(256) void k_qkv_qk(
    const bf16* __restrict__ Wb, const bf16* __restrict__ Wlo,
    const float* __restrict__ biasf, const char* __restrict__ SX,
    bf16* __restrict__ QT, bf16* __restrict__ KT)
{
    __shared__ __bf16 Ah_[3][64][32], Al_[3][64][32], Bh_[3][64][32], Bl_[3][64][32];
    int z, mc; tile_decode(blockIdx.x, gridDim.x, z, mc);
    int n0 = (mc >> 1) * 64;
    int m0 = (mc & 1) * 64;                // 0 -> q rows, 64 -> k rows
    const bf16* xTh = (const bf16*)(SX + (size_t)z * 4194304);
    const bf16* xTl = xTh + 524288;
    bf16* qt = QT + (size_t)z * 65536;
    bf16* kt = KT + (size_t)z * 65536;
    int tid = threadIdx.x, wave = tid >> 6, lane = tid & 63, quad = lane >> 4, l16 = lane & 15;
    int wmh = (wave >> 1) * 32, wnh = (wave & 1) * 32;

    const bf16* Ahr = Wb  + (size_t)m0 * C_IN;
    const bf16* Alr = Wlo + (size_t)m0 * C_IN;
    const bf16* Bhr = xTh + (size_t)n0 * C_IN;
    const bf16* Blr = xTl + (size_t)n0 * C_IN;

    f32x4 acc[2][2];
#pragma unroll
    for (int i = 0; i < 2; ++i)
#pragma unroll
        for (int j = 0; j < 2; ++j) acc[i][j] = (f32x4){0.f, 0.f, 0.f, 0.f};

    STAGE64(Ah_[0], Ahr, C_IN, 0);  STAGE64(Al_[0], Alr, C_IN, 0);
    STAGE64(Bh_[0], Bhr, C_IN, 0);  STAGE64(Bl_[0], Blr, C_IN, 0);
    STAGE64(Ah_[1], Ahr, C_IN, 32); STAGE64(Al_[1], Alr, C_IN, 32);
    STAGE64(Bh_[1], Bhr, C_IN, 32); STAGE64(Bl_[1], Blr, C_IN, 32);
    char *ah0 = (char*)Ah_[0], *ah1 = (char*)Ah_[1], *ah2 = (char*)Ah_[2];
    char *al0 = (char*)Al_[0], *al1 = (char*)Al_[1], *al2 = (char*)Al_[2];
    char *bh0 = (char*)Bh_[0], *bh1 = (char*)Bh_[1], *bh2 = (char*)Bh_[2];
    char *bl0 = (char*)Bl_[0], *bl1 = (char*)Bl_[1], *bl2 = (char*)Bl_[2];

#define QK_MFMA(PAH, PAL, PBH, PBL) {                                          \
    bf16x8 fah[2], fal[2], fbh[2], fbl[2];                                     \
    _Pragma("unroll")                                                          \
    for (int i = 0; i < 2; ++i) {                                              \
        fah[i] = swz_frag(PAH, wmh + i * 16 + l16, quad);                      \
        fal[i] = swz_frag(PAL, wmh + i * 16 + l16, quad);                      \
    }                                                                          \
    _Pragma("unroll")                                                          \
    for (int j = 0; j < 2; ++j) {                                              \
        fbh[j] = swz_frag(PBH, wnh + j * 16 + l16, quad);                      \
        fbl[j] = swz_frag(PBL, wnh + j * 16 + l16, quad);                      \
    }                                                                          \
    __builtin_amdgcn_s_setprio(1);                                             \
    _Pragma("unroll")                                                          \
    for (int i = 0; i < 2; ++i)                                                \
        _Pragma("unroll")                                                      \
        for (int j = 0; j < 2; ++j) {                                          \
            acc[i][j] = __builtin_amdgcn_mfma_f32_16x16x32_bf16(fah[i], fbh[j], acc[i][j], 0, 0, 0); \
            acc[i][j] = __builtin_amdgcn_mfma_f32_16x16x32_bf16(fah[i], fbl[j], acc[i][j], 0, 0, 0); \
            acc[i][j] = __builtin_amdgcn_mfma_f32_16x16x32_bf16(fal[i], fbh[j], acc[i][j], 0, 0, 0); \
        }                                                                      \
    __builtin_amdgcn_s_setprio(0); }

    for (int t = 0; t < 15; ++t) {
        asm volatile("s_waitcnt vmcnt(4)" ::: "memory");
        __builtin_amdgcn_s_barrier();
        __builtin_amdgcn_sched_barrier(0);
        if (t + 2 < 16) {
            int k2 = (t + 2) * 32;
            STAGE64(ah2, Ahr, C_IN, k2); STAGE64(al2, Alr, C_IN, k2);
            STAGE64(bh2, Bhr, C_IN, k2); STAGE64(bl2, Blr, C_IN, k2);
        }
        QK_MFMA(ah0, al0, bh0, bl0);
        char* tp = ah0; ah0 = ah1; ah1 = ah2; ah2 = tp;
        tp = al0; al0 = al1; al1 = al2; al2 = tp;
        tp = bh0; bh0 = bh1; bh1 = bh2; bh2 = tp;
        tp = bl0; bl0 = bl1; bl1 = bl2; bl2 = tp;
    }
    asm volatile("s_waitcnt vmcnt(0)" ::: "memory");
    __builtin_amdgcn_s_barrier();
    __builtin_amdgcn_sched_barrier(0);
    QK_MFMA(ah0, al0, bh0, bl0);
#undef QK_MFMA

#pragma unroll
    for (int i = 0; i < 2; ++i)
#pragma unroll
        for (int j = 0; j < 2; ++j) {
            int cbase = m0 + wmh + i * 16 + quad * 4;       // global row, +r (4 consecutive)
            int n = n0 + wnh + j * 16 + l16;
            ushort4 st;
            st.x = bfbits(acc[i][j][0] + biasf[cbase + 0]);
            st.y = bfbits(acc[i][j][1] + biasf[cbase + 1]);
            st.z = bfbits(acc[i][j][2] + biasf[cbase + 2]);
            st.w = bfbits(acc[i][j][3] + biasf[cbase + 3]);
            bf16* dst = (m0 == 0) ? &qt[(size_t)n * 64 + cbase]
                                  : &kt[(size_t)n * 64 + (cbase - 64)];
            *reinterpret_cast<ushort4*>(dst) = st;           // 8 B, aligned
        }
}

// ---------------------------------------------------------------------------
// K6: scores MFMA. S[m][n] = sum_o kt[m][o] * qt[n][o], fp32 out (over dead xT).
// 128x128 tile, K=64 (2 x BK=32), 4 waves x 4x4. (K too short to pipeline.)
// ---------------------------------------------------------------------------
__global__ __launch_bounds__(256) void k_qk(
    const bf16* __restrict__ QT, const bf16* __restrict__ KT,
    char* __restrict__ SX)
{
    __shared__ __bf16 Als[128][40];
    __shared__ __bf16 Bls[128][40];
    int z = blockIdx.z, m0 = blockIdx.y * 128, n0 = blockIdx.x * 128;
    const bf16* qt = QT + (size_t)z * 65536;
    const bf16* kt = KT + (size_t)z * 65536;
    float* Sf = (float*)(SX + (size_t)z * 4194304);
    int tid = threadIdx.x, wave = tid >> 6, lane = tid & 63, quad = lane >> 4, l16 = lane & 15;
    int wc = (wave >> 1) * 64, wm = (wave & 1) * 64;

    f32x4 acc[4][4];
#pragma unroll
    for (int i = 0; i < 4; ++i)
#pragma unroll
        for (int j = 0; j < 4; ++j) acc[i][j] = (f32x4){0.f, 0.f, 0.f, 0.f};

#pragma unroll
    for (int k0 = 0; k0 < 64; k0 += 32) {
#pragma unroll
        for (int s = 0; s < 2; ++s) {
            int idx = tid + s * 256; int row = idx >> 2, ch = idx & 3;
            *reinterpret_cast<uint4*>(&Als[row][ch * 8]) =
                *reinterpret_cast<const uint4*>(&kt[(size_t)(m0 + row) * 64 + k0 + ch * 8]);
            *reinterpret_cast<uint4*>(&Bls[row][ch * 8]) =
                *reinterpret_cast<const uint4*>(&qt[(size_t)(n0 + row) * 64 + k0 + ch * 8]);
        }
        __syncthreads();
        bf16x8 a[4], b[4];
#pragma unroll
        for (int i = 0; i < 4; ++i)
            a[i] = *reinterpret_cast<const bf16x8*>(&Als[wc + i * 16 + l16][quad * 8]);
#pragma unroll
        for (int j = 0; j < 4; ++j)
            b[j] = *reinterpret_cast<const bf16x8*>(&Bls[wm + j * 16 + l16][quad * 8]);
#pragma unroll
        for (int i = 0; i < 4; ++i)
#pragma unroll
            for (int j = 0; j < 4; ++j)
                acc[i][j] = __builtin_amdgcn_mfma_f32_16x16x32_bf16(a[i], b[j], acc[i][j], 0, 0, 0);
        __syncthreads();
    }
#pragma unroll
    for (int i = 0; i < 4; ++i)
#pragma unroll
        for (int j = 0; j < 4; ++j)
#pragma unroll
            for (int r = 0; r < 4; ++r) {
                int m = m0 + wc + i * 16 + quad * 4 + r;
                int n = n0 + wm + j * 16 + l16;
                Sf[(size_t)m * N_SP + n] = acc[i][j][r];
            }
}

// ---------------------------------------------------------------------------
// K7: row softmax, fp32 in -> bf16 P written IN PLACE (row owned by block).
// ---------------------------------------------------------------------------
__global__ __launch_bounds__(256) void k_softmax(char* __restrict__ SX)
{
    __shared__ float red[256];
    int z = blockIdx.x >> 10, m = blockIdx.x & 1023;
    float* p = (float*)(SX + (size_t)z * 4194304) + (size_t)m * N_SP;
    bf16* pb = (bf16*)p;
    int tid = threadIdx.x;
    float v0 = p[tid], v1 = p[tid + 256], v2 = p[tid + 512], v3 = p[tid + 768];
    red[tid] = fmaxf(fmaxf(v0, v1), fmaxf(v2, v3));
    __syncthreads();
    for (int s = 128; s > 0; s >>= 1) { if (tid < s) red[tid] = fmaxf(red[tid], red[tid + s]); __syncthreads(); }
    float mx = red[0];
    __syncthreads();
    float d0 = fmaxf(fminf(v0 - mx, 0.f), -80.f);
    float d1 = fmaxf(fminf(v1 - mx, 0.f), -80.f);
    float d2 = fmaxf(fminf(v2 - mx, 0.f), -80.f);
    float d3 = fmaxf(fminf(v3 - mx, 0.f), -80.f);
    float e0 = __expf(d0), e1 = __expf(d1), e2 = __expf(d2), e3 = __expf(d3);
    red[tid] = e0 + e1 + e2 + e3;
    __syncthreads();
    for (int s = 128; s > 0; s >>= 1) { if (tid < s) red[tid] += red[tid + s]; __syncthreads(); }
    float inv = 1.f / red[0];
    pb[tid]       = __float2bfloat16(e0 * inv);
    pb[tid + 256] = __float2bfloat16(e1 * inv);
    pb[tid + 512] = __float2bfloat16(e2 * inv);
    pb[tid + 768] = __float2bfloat16(e3 * inv);
}

// ---------------------------------------------------------------------------
// K8: output MFMA, 128x256 tile, BK=32, 8 waves, 3-buffer depth-2 counted
// pipeline, 72 KB dynamic LDS -> 2 blocks/CU.
// out[c][m] = gamma * sum_n Yv[c][n]*P[m][n] + x[c][m]. P pitch 2048 bf16.
// ---------------------------------------------------------------------------
__global__ __launch_bounds__(512, 4) void k_out(
    const bf16* __restrict__ YV, const char* __restrict__ SX,
    const void* __restrict__ x, const void* __restrict__ gamma,
    const int* __restrict__ flag, void* __restrict__ out, int batch0)
{
    extern __shared__ char lds[];
    int f32 = *flag;
    int z, mc; tile_decode16(blockIdx.x, gridDim.x, z, mc);
    int c0 = (mc >> 2) * 128;              // 4 c-tiles of 128
    int m0 = (mc & 3) * 256;               // 4 m-tiles of 256
    const bf16* Yv = YV + (size_t)z * 524288;
    const bf16* Pb = (const bf16*)(SX + (size_t)z * 4194304);   // pitch 2048
    int tid = threadIdx.x, wave = tid >> 6, lane = tid & 63, quad = lane >> 4, l16 = lane & 15;
    int wr = wave >> 2, wc4 = wave & 3;

    const bf16* Ar = Yv + (size_t)c0 * N_SP;
    const bf16* Br = Pb + (size_t)m0 * 2048;

    f32x4 acc[4][4];
#pragma unroll
    for (int i = 0; i < 4; ++i)
#pragma unroll
        for (int j = 0; j < 4; ++j) acc[i][j] = (f32x4){0.f, 0.f, 0.f, 0.f};

    STGU(lds,         Ar, N_SP, Br, 2048, 0);
    STGU(lds + 24576, Ar, N_SP, Br, 2048, 32);

#define O_MFMA(UB) {                                                           \
    bf16x8 af[4], bfr[4];                                                      \
    _Pragma("unroll")                                                          \
    for (int fm = 0; fm < 4; ++fm)                                             \
        af[fm] = frag32(UB, wr * 64 + fm * 16 + l16, quad);                    \
    _Pragma("unroll")                                                          \
    for (int fn = 0; fn < 4; ++fn)                                             \
        bfr[fn] = frag32((UB) + 8192, wc4 * 64 + fn * 16 + l16, quad);         \
    __builtin_amdgcn_s_setprio(1);                                             \
    _Pragma("unroll")                                                          \
    for (int fm = 0; fm < 4; ++fm)                                             \
        _Pragma("unroll")                                                      \
        for (int fn = 0; fn < 4; ++fn)                                         \
            acc[fm][fn] = __builtin_amdgcn_mfma_f32_16x16x32_bf16(af[fm], bfr[fn], acc[fm][fn], 0, 0, 0); \
    __builtin_amdgcn_s_setprio(0); }

    const int NT = 32;                      // K = 1024 = 32 x 32
    int bsel = 0;
    for (int t = 0; t < NT - 1; ++t) {
        WAITN_BARRIER(3);                  // unit t landed block-wide
        if (t + 2 < NT) {
            int nb = bsel + 2; if (nb >= 3) nb -= 3;
            STGU(lds + (size_t)nb * 24576, Ar, N_SP, Br, 2048, (t + 2) * 32);
        }
        O_MFMA(lds + (size_t)bsel * 24576);
        if (++bsel == 3) bsel = 0;
    }
    WAITN_BARRIER(0);
    O_MFMA(lds + (size_t)bsel * 24576);
#undef O_MFMA

    float g = ldmix(gamma, 0, f32);
    const size_t base = (size_t)(batch0 + z) * C_IN * N_SP;
#pragma unroll
    for (int fm = 0; fm < 4; ++fm)
#pragma unroll
        for (int fn = 0; fn < 4; ++fn)
#pragma unroll
            for (int r = 0; r < 4; ++r) {
                int c = c0 + wr * 64 + fm * 16 + quad * 4 + r;
                int m = m0 + wc4 * 64 + fn * 16 + l16;
                size_t o = base + (size_t)c * N_SP + m;
                float v = fmaf(g, acc[fm][fn][r], ldmix(x, o, f32));
                if (!(v == v)) v = 5555.0f + 1000.0f * f32;   // NaN sentinel
                stmix(out, o, v, f32);
            }
}

// Diagnostic: workspace too small even for GB=1.
__global__ void k_wsfail(float* __restrict__ out, int n)
{
    int i = blockIdx.x * 256 + threadIdx.x;
    if (i < n) out[i] = 7777.0f;
}

// ---------------------------------------------------------------------------
extern "C" void kernel_launch(void* const* d_in, const int* in_sizes, int n_in,
                              void* d_out, int out_size, void* d_ws, size_t ws_size,
                              hipStream_t stream)
{
    const void* x  = d_in[0];
    const void* Wq = d_in[1];
    const void* bq = d_in[2];
    const void* Wk = d_in[4];
    const void* bk = d_in[5];
    const void* Wv = d_in[7];
    const void* bv = d_in[8];
    const void* uq = d_in[3];
    const void* uk = d_in[6];
    const void* uv = d_in[9];
    const void* gm = d_in[10];

    // Allow 72 KB dynamic LDS for the 128x256 GEMMs (defensive; ignore errors).
    static int lds_opt_done = 0;
    if (!lds_opt_done) {
        (void)hipFuncSetAttribute(reinterpret_cast<const void*>(k_qkv_v),
                                  hipFuncAttributeMaxDynamicSharedMemorySize, 73728);
        (void)hipFuncSetAttribute(reinterpret_cast<const void*>(k_out),
                                  hipFuncAttributeMaxDynamicSharedMemorySize, 73728);
        lds_opt_done = 1;
    }

    // ws layout:
    //   flag @0, sig[3] @16, biasf[640] @256, Wb bf16[640][512] @4096,
    //   Wlo bf16[128][512] @659456 -> group region @790528:
    //     SX: GB x 4MB  (xT_hi 1MB | xT_lo 1MB | ...), later fp32 S overwrites
    //     QT: GB x 128KB, KT: GB x 128KB, YV: GB x 1MB
    //   tpart (spectral partials) aliases the head of SX (dead before k_xt).
    const size_t HDR = 790528;
    const size_t per = 4194304 + 131072 + 131072 + 1048576;   // 5,505,024
    int GB = 0;
    for (int g = 32; g >= 1; g >>= 1)
        if (HDR + (size_t)g * per <= ws_size) { GB = g; break; }
    if (GB == 0) {
        k_wsfail<<<(out_size + 255) / 256, 256, 0, stream>>>((float*)d_out, out_size);
        return;
    }
    char* ws = (char*)d_ws;
    int*   flag  = (int*)ws;
    float* sig   = (float*)(ws + 16);
    float* biasf = (float*)(ws + 256);
    bf16*  Wb    = (bf16*)(ws + 4096);
    bf16*  Wlo   = (bf16*)(ws + 659456);
    char*  SX    = ws + HDR;
    bf16*  QT    = (bf16*)(SX + (size_t)GB * 4194304);
    bf16*  KT    = QT + (size_t)GB * 65536;
    bf16*  YV    = KT + (size_t)GB * 65536;
    float* tpart = (float*)SX;    // dead before first k_xt write

    k_detect<<<1, 256, 0, stream>>>((const unsigned short*)x, flag);
    k_sn1<<<10, 256, 0, stream>>>(Wq, uq, Wk, uk, Wv, uv, flag, tpart);
    k_sn2<<<3, 512, 0, stream>>>(Wq, Wk, Wv, flag, tpart, sig);
    k_wscale<<<640, 256, 0, stream>>>(Wq, bq, Wk, bk, Wv, bv, sig, flag, Wb, Wlo, biasf);
    for (int b0 = 0; b0 < BATCH; b0 += GB) {
        k_xt     <<<dim3(16, 8, GB), 256, 0, stream>>>(x, flag, SX, b0);
        k_qkv_v  <<<GB * 16, 512, 73728, stream>>>(Wb, biasf, SX, YV);
        k_qkv_qk <<<GB * 32, 256, 0, stream>>>(Wb, Wlo, biasf, SX, QT, KT);
        k_qk     <<<dim3(8, 8, GB), 256, 0, stream>>>(QT, KT, SX);
        k_softmax<<<GB * 1024, 256, 0, stream>>>(SX);
        k_out    <<<GB * 16, 512, 73728, stream>>>(YV, SX, x, gm, flag, d_out, b0);
    }
}